// Round 1
// baseline (978.058 us; speedup 1.0000x reference)
//
#include <hip/hip_runtime.h>

#define NN 15360        // total nodes
#define NE 92160        // total edges
#define NE_ACT 34560    // edges with mask=1 (first B*(EQ+EC)); rest are masked to zero
#define BATCH 256
#define D 128
#define TT 64
#define NPG 60
#define NCC 30
#define NQQ 15
#define NPROP 5
#define SKI 10

// ---------------- node encode: h[i,d] = nf[i]*w[d]+b[d] ----------------
__global__ void k_encode(const float* __restrict__ nf, const float* __restrict__ w,
                         const float* __restrict__ b, float* __restrict__ h) {
    int idx = blockIdx.x * 256 + threadIdx.x;
    if (idx >= NN * D) return;
    int d = idx & (D - 1);
    int i = idx >> 7;
    h[idx] = nf[i] * w[d] + b[d];
}

// ---------------- edge-constant precompute: u,v (256 each) ----------------
// e @ W1c = ef*u + v0 ; v = v0 + msg_b1
__global__ void k_prep_uv(const float* __restrict__ ew, const float* __restrict__ eb,
                          const float* __restrict__ w1, const float* __restrict__ b1,
                          float* __restrict__ uv) {
    int t = threadIdx.x;  // 0..255
    float u = 0.f, v = 0.f;
    for (int d = 0; d < D; ++d) {
        float wv = w1[(256 + d) * 256 + t];
        u += ew[d] * wv;
        v += eb[d] * wv;
    }
    uv[t] = u;
    uv[256 + t] = v + b1[t];
}

// ---------------- GEMM1: H1(N x 512) = h(N x 128) @ [W1a ; W1b] ----------------
// cols 0..255: sum_k h[m,k]*w1[k,c] ; cols 256..511: sum_k h[m,k]*w1[128+k,c-256]
__global__ __launch_bounds__(256) void k_h1(const float* __restrict__ h,
                                            const float* __restrict__ w1,
                                            float* __restrict__ H1) {
    __shared__ float As[16][68];
    __shared__ float Bs[16][68];
    int m0 = blockIdx.x * 64, n0 = blockIdx.y * 64;
    int tid = threadIdx.x;
    int tx = tid & 15, ty = tid >> 4;
    const int kl = tid & 15, ml = tid >> 4;
    const int kb = tid >> 6, nb = tid & 63;
    float acc[4][4] = {};
    for (int k0 = 0; k0 < 128; k0 += 16) {
#pragma unroll
        for (int p = 0; p < 4; p++) {
            int m = ml + p * 16;
            As[kl][m] = h[(size_t)(m0 + m) * D + k0 + kl];
        }
        int n = n0 + nb;
#pragma unroll
        for (int p = 0; p < 4; p++) {
            int k = kb + p * 4;
            float bv = (n < 256) ? w1[(k0 + k) * 256 + n]
                                 : w1[(128 + k0 + k) * 256 + (n - 256)];
            Bs[k][nb] = bv;
        }
        __syncthreads();
#pragma unroll
        for (int kk = 0; kk < 16; ++kk) {
            float4 av = *(const float4*)&As[kk][ty * 4];
            float4 bv = *(const float4*)&Bs[kk][tx * 4];
            float a_[4] = {av.x, av.y, av.z, av.w};
            float b_[4] = {bv.x, bv.y, bv.z, bv.w};
#pragma unroll
            for (int i = 0; i < 4; i++)
#pragma unroll
                for (int j = 0; j < 4; j++) acc[i][j] += a_[i] * b_[j];
        }
        __syncthreads();
    }
#pragma unroll
    for (int i = 0; i < 4; i++)
#pragma unroll
        for (int j = 0; j < 4; j++)
            H1[(size_t)(m0 + ty * 4 + i) * 512 + n0 + tx * 4 + j] = acc[i][j];
}

// ---------------- edge GEMM: msg = relu(Z) @ W2 + b2, scatter-add (mask) ----------------
// Z[e,k] = H1[from[e],k] + H1[to[e],256+k] + ef[e]*u[k] + v[k]
__global__ __launch_bounds__(256) void k_edge(const float* __restrict__ H1,
                                              const float* __restrict__ uv,
                                              const int* __restrict__ fr,
                                              const int* __restrict__ to,
                                              const float* __restrict__ ef,
                                              const float* __restrict__ mfi,
                                              const float* __restrict__ w2,
                                              const float* __restrict__ b2,
                                              float* __restrict__ agg) {
    __shared__ float As[16][68];
    __shared__ float Bs[16][68];
    __shared__ int frs[64];
    __shared__ int tos[64];
    __shared__ float efs[64];
    __shared__ float ms[64];
    int e0 = blockIdx.x * 64, n0 = blockIdx.y * 64;
    int tid = threadIdx.x;
    if (tid < 64) {
        frs[tid] = fr[e0 + tid];
        tos[tid] = to[e0 + tid];
        efs[tid] = ef[e0 + tid];
        ms[tid] = mfi[e0 + tid];
    }
    __syncthreads();
    int tx = tid & 15, ty = tid >> 4;
    const int kl = tid & 15, el = tid >> 4;
    const int kb = tid >> 6, nb = tid & 63;
    float acc[4][4] = {};
    for (int k0 = 0; k0 < 256; k0 += 16) {
        int k = k0 + kl;
#pragma unroll
        for (int p = 0; p < 4; p++) {
            int e = el + p * 16;
            float z = H1[(size_t)frs[e] * 512 + k] + H1[(size_t)tos[e] * 512 + 256 + k] +
                      efs[e] * uv[k] + uv[256 + k];
            As[kl][e] = fmaxf(z, 0.f);
        }
#pragma unroll
        for (int p = 0; p < 4; p++) {
            int kr = kb + p * 4;
            Bs[kr][nb] = w2[(k0 + kr) * 128 + n0 + nb];
        }
        __syncthreads();
#pragma unroll
        for (int kk = 0; kk < 16; ++kk) {
            float4 av = *(const float4*)&As[kk][ty * 4];
            float4 bv = *(const float4*)&Bs[kk][tx * 4];
            float a_[4] = {av.x, av.y, av.z, av.w};
            float b_[4] = {bv.x, bv.y, bv.z, bv.w};
#pragma unroll
            for (int i = 0; i < 4; i++)
#pragma unroll
                for (int j = 0; j < 4; j++) acc[i][j] += a_[i] * b_[j];
        }
        __syncthreads();
    }
#pragma unroll
    for (int i = 0; i < 4; i++) {
        int e = ty * 4 + i;
        int toi = tos[e];
        float mv = ms[e];
#pragma unroll
        for (int j = 0; j < 4; j++) {
            int n = n0 + tx * 4 + j;
            atomicAdd(&agg[(size_t)toi * D + n], (acc[i][j] + b2[n]) * mv);
        }
    }
}

// ---------------- upd layer1: U = relu([agg,h] @ Wu1 + b1)  (N x 256) ----------------
__global__ __launch_bounds__(256) void k_upd1(const float* __restrict__ agg,
                                              const float* __restrict__ h,
                                              const float* __restrict__ w,
                                              const float* __restrict__ b,
                                              float* __restrict__ U) {
    __shared__ float As[16][68];
    __shared__ float Bs[16][68];
    int m0 = blockIdx.x * 64, n0 = blockIdx.y * 64;
    int tid = threadIdx.x;
    int tx = tid & 15, ty = tid >> 4;
    const int kl = tid & 15, ml = tid >> 4;
    const int kb = tid >> 6, nb = tid & 63;
    float acc[4][4] = {};
    for (int k0 = 0; k0 < 256; k0 += 16) {
        int k = k0 + kl;
#pragma unroll
        for (int p = 0; p < 4; p++) {
            int m = m0 + ml + p * 16;
            As[kl][ml + p * 16] =
                (k < 128) ? agg[(size_t)m * D + k] : h[(size_t)m * D + k - 128];
        }
#pragma unroll
        for (int p = 0; p < 4; p++) {
            int kr = kb + p * 4;
            Bs[kr][nb] = w[(k0 + kr) * 256 + n0 + nb];
        }
        __syncthreads();
#pragma unroll
        for (int kk = 0; kk < 16; ++kk) {
            float4 av = *(const float4*)&As[kk][ty * 4];
            float4 bv = *(const float4*)&Bs[kk][tx * 4];
            float a_[4] = {av.x, av.y, av.z, av.w};
            float b_[4] = {bv.x, bv.y, bv.z, bv.w};
#pragma unroll
            for (int i = 0; i < 4; i++)
#pragma unroll
                for (int j = 0; j < 4; j++) acc[i][j] += a_[i] * b_[j];
        }
        __syncthreads();
    }
#pragma unroll
    for (int i = 0; i < 4; i++)
#pragma unroll
        for (int j = 0; j < 4; j++) {
            int n = n0 + tx * 4 + j;
            U[(size_t)(m0 + ty * 4 + i) * 256 + n] = fmaxf(acc[i][j] + b[n], 0.f);
        }
}

// ---------------- upd layer2: h += U @ Wu2 + b2 ----------------
__global__ __launch_bounds__(256) void k_upd2(const float* __restrict__ U,
                                              const float* __restrict__ w,
                                              const float* __restrict__ b,
                                              float* __restrict__ h) {
    __shared__ float As[16][68];
    __shared__ float Bs[16][68];
    int m0 = blockIdx.x * 64, n0 = blockIdx.y * 64;
    int tid = threadIdx.x;
    int tx = tid & 15, ty = tid >> 4;
    const int kl = tid & 15, ml = tid >> 4;
    const int kb = tid >> 6, nb = tid & 63;
    float acc[4][4] = {};
    for (int k0 = 0; k0 < 256; k0 += 16) {
        int k = k0 + kl;
#pragma unroll
        for (int p = 0; p < 4; p++) {
            int m = m0 + ml + p * 16;
            As[kl][ml + p * 16] = U[(size_t)m * 256 + k];
        }
#pragma unroll
        for (int p = 0; p < 4; p++) {
            int kr = kb + p * 4;
            Bs[kr][nb] = w[(k0 + kr) * 128 + n0 + nb];
        }
        __syncthreads();
#pragma unroll
        for (int kk = 0; kk < 16; ++kk) {
            float4 av = *(const float4*)&As[kk][ty * 4];
            float4 bv = *(const float4*)&Bs[kk][tx * 4];
            float a_[4] = {av.x, av.y, av.z, av.w};
            float b_[4] = {bv.x, bv.y, bv.z, bv.w};
#pragma unroll
            for (int i = 0; i < 4; i++)
#pragma unroll
                for (int j = 0; j < 4; j++) acc[i][j] += a_[i] * b_[j];
        }
        __syncthreads();
    }
#pragma unroll
    for (int i = 0; i < 4; i++)
#pragma unroll
        for (int j = 0; j < 4; j++) {
            int n = n0 + tx * 4 + j;
            size_t o = (size_t)(m0 + ty * 4 + i) * D + n;
            h[o] = h[o] + acc[i][j] + b[n];
        }
}

// ---------------- final transform: t = relu(h@ft1+b1)@ft2+b2, q-mask ----------------
__global__ __launch_bounds__(64) void k_transform(const float* __restrict__ h,
                                                  const float* __restrict__ w1,
                                                  const float* __restrict__ b1,
                                                  const float* __restrict__ w2,
                                                  const float* __restrict__ b2,
                                                  float* __restrict__ tout) {
    __shared__ float row[D];
    __shared__ float hid[TT];
    int i = blockIdx.x;
    int j = threadIdx.x;  // 0..63
    row[j] = h[(size_t)i * D + j];
    row[j + 64] = h[(size_t)i * D + j + 64];
    __syncthreads();
    float s = b1[j];
    for (int k = 0; k < D; k++) s += row[k] * w1[k * TT + j];
    hid[j] = fmaxf(s, 0.f);
    __syncthreads();
    float o = b2[j];
    for (int k = 0; k < TT; k++) o += hid[k] * w2[k * TT + j];
    int p = i % NPG;
    if (p >= NQQ && p < NCC) o = 0.f;  // q-part rows >= NQ are masked
    tout[(size_t)i * TT + j] = o;
}

// ---------------- per-graph Sinkhorn + scoring ----------------
__global__ __launch_bounds__(256) void k_sinkhorn(const float* __restrict__ h,
                                                  const float* __restrict__ tall,
                                                  float* __restrict__ out) {
    __shared__ float la[NCC * NCC];
    __shared__ float tqs[NCC][TT];
    __shared__ float tcs[NCC][TT];
    __shared__ float ce[NCC][D];
    __shared__ float lse[NCC];
    __shared__ float red[256];
    int g = blockIdx.x;
    int tid = threadIdx.x;
    for (int idx = tid; idx < NCC * TT; idx += 256) {
        int r = idx / TT, k = idx % TT;
        tqs[r][k] = tall[(size_t)(g * NPG + r) * TT + k];
        tcs[r][k] = tall[(size_t)(g * NPG + NCC + r) * TT + k];
    }
    for (int idx = tid; idx < NCC * D; idx += 256) {
        int c = idx / D, d = idx % D;
        ce[c][d] = h[(size_t)(g * NPG + NCC + c) * D + d];
    }
    __syncthreads();
    for (int e = tid; e < NCC * NCC; e += 256) {
        int q = e / NCC, c = e % NCC;
        float s = 0.f;
        for (int k = 0; k < TT; k++) s += tqs[q][k] * tcs[c][k];
        la[e] = s * 10.0f;  // / SK_TEMP
    }
    __syncthreads();
    for (int it = 0; it < SKI; ++it) {
        if (tid < NCC) {
            float m = -INFINITY;
            for (int c = 0; c < NCC; c++) m = fmaxf(m, la[tid * NCC + c]);
            float s = 0.f;
            for (int c = 0; c < NCC; c++) s += expf(la[tid * NCC + c] - m);
            lse[tid] = m + logf(s);
        }
        __syncthreads();
        for (int e = tid; e < NCC * NCC; e += 256) la[e] -= lse[e / NCC];
        __syncthreads();
        if (tid < NCC) {
            float m = -INFINITY;
            for (int q = 0; q < NCC; q++) m = fmaxf(m, la[q * NCC + tid]);
            float s = 0.f;
            for (int q = 0; q < NCC; q++) s += expf(la[q * NCC + tid] - m);
            lse[tid] = m + logf(s);
        }
        __syncthreads();
        for (int e = tid; e < NCC * NCC; e += 256) la[e] -= lse[e % NCC];
        __syncthreads();
    }
    for (int e = tid; e < NCC * NCC; e += 256) la[e] = expf(la[e]);
    __syncthreads();
    float part = 0.f;
    for (int idx = tid; idx < NCC * D; idx += 256) {
        int q = idx / D, d = idx % D;
        float mv = 0.f;
        for (int c = 0; c < NCC; c++) mv += la[q * NCC + c] * ce[c][d];
        float qe = h[(size_t)(g * NPG + q) * D + d];
        part += fmaxf(qe - mv, 0.f);
    }
    red[tid] = part;
    __syncthreads();
    for (int s2 = 128; s2 > 0; s2 >>= 1) {
        if (tid < s2) red[tid] += red[tid + s2];
        __syncthreads();
    }
    if (tid == 0) out[g] = -red[0];
}

extern "C" void kernel_launch(void* const* d_in, const int* in_sizes, int n_in,
                              void* d_out, int out_size, void* d_ws, size_t ws_size,
                              hipStream_t stream) {
    const float* nf  = (const float*)d_in[0];
    const float* ef  = (const float*)d_in[1];
    const float* mfi = (const float*)d_in[2];
    const float* enw = (const float*)d_in[3];
    const float* enb = (const float*)d_in[4];
    const float* eew = (const float*)d_in[5];
    const float* eeb = (const float*)d_in[6];
    const float* mw1 = (const float*)d_in[7];
    const float* mb1 = (const float*)d_in[8];
    const float* mw2 = (const float*)d_in[9];
    const float* mb2 = (const float*)d_in[10];
    const float* uw1 = (const float*)d_in[11];
    const float* ub1 = (const float*)d_in[12];
    const float* uw2 = (const float*)d_in[13];
    const float* ub2 = (const float*)d_in[14];
    const float* f1w = (const float*)d_in[15];
    const float* f1b = (const float*)d_in[16];
    const float* f2w = (const float*)d_in[17];
    const float* f2b = (const float*)d_in[18];
    const int* fr = (const int*)d_in[19];
    const int* to = (const int*)d_in[20];
    float* out = (float*)d_out;

    float* ws   = (float*)d_ws;
    float* h    = ws;                           // NN*128
    float* H1   = h + (size_t)NN * D;           // NN*512 (reused as U after edge pass)
    float* agg  = H1 + (size_t)NN * 512;        // NN*128
    float* uv   = agg + (size_t)NN * D;         // 512
    float* tall = uv + 512;                     // NN*64

    k_encode<<<(NN * D + 255) / 256, 256, 0, stream>>>(nf, enw, enb, h);
    k_prep_uv<<<1, 256, 0, stream>>>(eew, eeb, mw1, mb1, uv);

    for (int it = 0; it < NPROP; ++it) {
        k_h1<<<dim3(NN / 64, 8), 256, 0, stream>>>(h, mw1, H1);
        hipMemsetAsync(agg, 0, (size_t)NN * D * sizeof(float), stream);
        // only the first NE_ACT edges have nonzero mask; the rest contribute 0
        k_edge<<<dim3(NE_ACT / 64, 2), 256, 0, stream>>>(H1, uv, fr, to, ef, mfi, mw2,
                                                         mb2, agg);
        k_upd1<<<dim3(NN / 64, 4), 256, 0, stream>>>(agg, h, uw1, ub1, H1);
        k_upd2<<<dim3(NN / 64, 2), 256, 0, stream>>>(H1, uw2, ub2, h);
    }

    k_transform<<<NN, 64, 0, stream>>>(h, f1w, f1b, f2w, f2b, tall);
    k_sinkhorn<<<BATCH, 256, 0, stream>>>(h, tall, out);
}

// Round 2
// 956.523 us; speedup vs baseline: 1.0225x; 1.0225x over previous
//
#include <hip/hip_runtime.h>

#define NN 15360        // total nodes
#define NC_ROWS 11520   // compacted H1 rows: 45 per graph (q 0..14, c 30..59)
#define EPG 135         // active edges per graph (EQ=45 + EC=90), contiguous per graph
#define BATCH 256
#define D 128
#define TT 64
#define NPG 60
#define NCC 30
#define NQQ 15
#define NPROP 5
#define SKI 10

// ---------------- node encode: h[i,d] = nf[i]*w[d]+b[d] ----------------
__global__ void k_encode(const float* __restrict__ nf, const float* __restrict__ w,
                         const float* __restrict__ b, float* __restrict__ h) {
    int idx = blockIdx.x * 256 + threadIdx.x;
    if (idx >= NN * D) return;
    int d = idx & (D - 1);
    int i = idx >> 7;
    h[idx] = nf[i] * w[d] + b[d];
}

// ---------------- edge-constant precompute: u,v (256 each) ----------------
__global__ void k_prep_uv(const float* __restrict__ ew, const float* __restrict__ eb,
                          const float* __restrict__ w1, const float* __restrict__ b1,
                          float* __restrict__ uv) {
    int t = threadIdx.x;  // 0..255
    float u = 0.f, v = 0.f;
    for (int d = 0; d < D; ++d) {
        float wv = w1[(256 + d) * 256 + t];
        u += ew[d] * wv;
        v += eb[d] * wv;
    }
    uv[t] = u;
    uv[256 + t] = v + b1[t];
}

// ---------------- GEMM1 (compact): H1c(11520 x 512) = h[sel] @ [W1a ; W1b] ----------------
__global__ __launch_bounds__(256) void k_h1c(const float* __restrict__ h,
                                             const float* __restrict__ w1,
                                             float* __restrict__ H1c) {
    __shared__ float As[16][68];
    __shared__ float Bs[16][68];
    __shared__ int rowNode[64];
    int m0 = blockIdx.x * 64, n0 = blockIdx.y * 64;
    int tid = threadIdx.x;
    if (tid < 64) {
        int m = m0 + tid;
        int g = m / 45;
        int p = m - g * 45;
        rowNode[tid] = g * 60 + (p < 15 ? p : p + 15);
    }
    __syncthreads();
    int tx = tid & 15, ty = tid >> 4;
    const int kl = tid & 15, ml = tid >> 4;
    const int kb = tid >> 6, nb = tid & 63;
    float acc[4][4] = {};
    for (int k0 = 0; k0 < 128; k0 += 16) {
#pragma unroll
        for (int p = 0; p < 4; p++) {
            int m = ml + p * 16;
            As[kl][m] = h[(size_t)rowNode[m] * D + k0 + kl];
        }
        int n = n0 + nb;
#pragma unroll
        for (int p = 0; p < 4; p++) {
            int k = kb + p * 4;
            float bv = (n < 256) ? w1[(k0 + k) * 256 + n]
                                 : w1[(128 + k0 + k) * 256 + (n - 256)];
            Bs[k][nb] = bv;
        }
        __syncthreads();
#pragma unroll
        for (int kk = 0; kk < 16; ++kk) {
            float4 av = *(const float4*)&As[kk][ty * 4];
            float4 bv = *(const float4*)&Bs[kk][tx * 4];
            float a_[4] = {av.x, av.y, av.z, av.w};
            float b_[4] = {bv.x, bv.y, bv.z, bv.w};
#pragma unroll
            for (int i = 0; i < 4; i++)
#pragma unroll
                for (int j = 0; j < 4; j++) acc[i][j] += a_[i] * b_[j];
        }
        __syncthreads();
    }
#pragma unroll
    for (int i = 0; i < 4; i++)
#pragma unroll
        for (int j = 0; j < 4; j++)
            H1c[(size_t)(m0 + ty * 4 + i) * 512 + n0 + tx * 4 + j] = acc[i][j];
}

// ---------------- per-graph edge pass: gather+relu, GEMM, LDS-agg, store ----------------
// block = (graph g, n-half). M-tiles of 48 cover 135 edges (144 padded).
__global__ __launch_bounds__(256) void k_edge_g(const float* __restrict__ H1c,
                                                const float* __restrict__ uv,
                                                const int* __restrict__ fr,
                                                const int* __restrict__ to,
                                                const float* __restrict__ ef,
                                                const float* __restrict__ mfi,
                                                const float* __restrict__ w2,
                                                const float* __restrict__ b2,
                                                float* __restrict__ agg) {
    __shared__ float As[16][52];
    __shared__ float Bs[16][68];
    __shared__ float aggl[NPG][64];
    __shared__ int cfs[144];   // compact from-row in H1c
    __shared__ int ctc[144];   // compact to-row in H1c
    __shared__ int ctl[144];   // local to-node 0..59
    __shared__ float efs[144];
    __shared__ float ms[144];
    int g = blockIdx.x;
    int n0 = blockIdx.y * 64;
    int tid = threadIdx.x;
    int e0 = g * EPG;
    if (tid < 144) {
        if (tid < EPG) {
            int f = fr[e0 + tid] - g * 60;
            int t = to[e0 + tid] - g * 60;
            cfs[tid] = g * 45 + (f < 15 ? f : f - 15);
            ctc[tid] = g * 45 + (t < 15 ? t : t - 15);
            ctl[tid] = t;
            efs[tid] = ef[e0 + tid];
            ms[tid] = mfi[e0 + tid];
        } else {
            cfs[tid] = 0; ctc[tid] = 0; ctl[tid] = 0; efs[tid] = 0.f; ms[tid] = 0.f;
        }
    }
    for (int i = tid; i < NPG * 64; i += 256) (&aggl[0][0])[i] = 0.f;
    __syncthreads();
    int tx = tid & 15, ty = tid >> 4;
    const int kl = tid & 15, el = tid >> 4;
    const int kb = tid >> 6, nb = tid & 63;
    for (int mt = 0; mt < 3; ++mt) {
        int eb0 = mt * 48;
        float acc[3][4] = {};
        for (int k0 = 0; k0 < 256; k0 += 16) {
            int k = k0 + kl;
#pragma unroll
            for (int p = 0; p < 3; p++) {
                int e = eb0 + el + p * 16;
                float z = H1c[(size_t)cfs[e] * 512 + k] +
                          H1c[(size_t)ctc[e] * 512 + 256 + k] + efs[e] * uv[k] +
                          uv[256 + k];
                As[kl][el + p * 16] = fmaxf(z, 0.f);
            }
#pragma unroll
            for (int p = 0; p < 4; p++) {
                int kr = kb + p * 4;
                Bs[kr][nb] = w2[(k0 + kr) * 128 + n0 + nb];
            }
            __syncthreads();
#pragma unroll
            for (int kk = 0; kk < 16; ++kk) {
                float a_[3];
#pragma unroll
                for (int i = 0; i < 3; i++) a_[i] = As[kk][ty * 3 + i];
                float4 bv = *(const float4*)&Bs[kk][tx * 4];
                float b_[4] = {bv.x, bv.y, bv.z, bv.w};
#pragma unroll
                for (int i = 0; i < 3; i++)
#pragma unroll
                    for (int j = 0; j < 4; j++) acc[i][j] += a_[i] * b_[j];
            }
            __syncthreads();
        }
#pragma unroll
        for (int i = 0; i < 3; i++) {
            int e = eb0 + ty * 3 + i;
            if (e < EPG) {
                int tl = ctl[e];
                float mv = ms[e];
#pragma unroll
                for (int j = 0; j < 4; j++) {
                    int n = tx * 4 + j;
                    atomicAdd(&aggl[tl][n], (acc[i][j] + b2[n0 + n]) * mv);
                }
            }
        }
        __syncthreads();
    }
    for (int i = tid; i < NPG * 64; i += 256) {
        int r = i >> 6, c = i & 63;
        agg[(size_t)(g * NPG + r) * D + n0 + c] = aggl[r][c];
    }
}

// ---------------- upd layer1: U = relu([agg,h] @ Wu1 + b1)  (N x 256) ----------------
__global__ __launch_bounds__(256) void k_upd1(const float* __restrict__ agg,
                                              const float* __restrict__ h,
                                              const float* __restrict__ w,
                                              const float* __restrict__ b,
                                              float* __restrict__ U) {
    __shared__ float As[16][68];
    __shared__ float Bs[16][68];
    int m0 = blockIdx.x * 64, n0 = blockIdx.y * 64;
    int tid = threadIdx.x;
    int tx = tid & 15, ty = tid >> 4;
    const int kl = tid & 15, ml = tid >> 4;
    const int kb = tid >> 6, nb = tid & 63;
    float acc[4][4] = {};
    for (int k0 = 0; k0 < 256; k0 += 16) {
        int k = k0 + kl;
#pragma unroll
        for (int p = 0; p < 4; p++) {
            int m = m0 + ml + p * 16;
            As[kl][ml + p * 16] =
                (k < 128) ? agg[(size_t)m * D + k] : h[(size_t)m * D + k - 128];
        }
#pragma unroll
        for (int p = 0; p < 4; p++) {
            int kr = kb + p * 4;
            Bs[kr][nb] = w[(k0 + kr) * 256 + n0 + nb];
        }
        __syncthreads();
#pragma unroll
        for (int kk = 0; kk < 16; ++kk) {
            float4 av = *(const float4*)&As[kk][ty * 4];
            float4 bv = *(const float4*)&Bs[kk][tx * 4];
            float a_[4] = {av.x, av.y, av.z, av.w};
            float b_[4] = {bv.x, bv.y, bv.z, bv.w};
#pragma unroll
            for (int i = 0; i < 4; i++)
#pragma unroll
                for (int j = 0; j < 4; j++) acc[i][j] += a_[i] * b_[j];
        }
        __syncthreads();
    }
#pragma unroll
    for (int i = 0; i < 4; i++)
#pragma unroll
        for (int j = 0; j < 4; j++) {
            int n = n0 + tx * 4 + j;
            U[(size_t)(m0 + ty * 4 + i) * 256 + n] = fmaxf(acc[i][j] + b[n], 0.f);
        }
}

// ---------------- upd layer2: h += U @ Wu2 + b2 ----------------
__global__ __launch_bounds__(256) void k_upd2(const float* __restrict__ U,
                                              const float* __restrict__ w,
                                              const float* __restrict__ b,
                                              float* __restrict__ h) {
    __shared__ float As[16][68];
    __shared__ float Bs[16][68];
    int m0 = blockIdx.x * 64, n0 = blockIdx.y * 64;
    int tid = threadIdx.x;
    int tx = tid & 15, ty = tid >> 4;
    const int kl = tid & 15, ml = tid >> 4;
    const int kb = tid >> 6, nb = tid & 63;
    float acc[4][4] = {};
    for (int k0 = 0; k0 < 256; k0 += 16) {
        int k = k0 + kl;
#pragma unroll
        for (int p = 0; p < 4; p++) {
            int m = m0 + ml + p * 16;
            As[kl][ml + p * 16] = U[(size_t)m * 256 + k];
        }
#pragma unroll
        for (int p = 0; p < 4; p++) {
            int kr = kb + p * 4;
            Bs[kr][nb] = w[(k0 + kr) * 128 + n0 + nb];
        }
        __syncthreads();
#pragma unroll
        for (int kk = 0; kk < 16; ++kk) {
            float4 av = *(const float4*)&As[kk][ty * 4];
            float4 bv = *(const float4*)&Bs[kk][tx * 4];
            float a_[4] = {av.x, av.y, av.z, av.w};
            float b_[4] = {bv.x, bv.y, bv.z, bv.w};
#pragma unroll
            for (int i = 0; i < 4; i++)
#pragma unroll
                for (int j = 0; j < 4; j++) acc[i][j] += a_[i] * b_[j];
        }
        __syncthreads();
    }
#pragma unroll
    for (int i = 0; i < 4; i++)
#pragma unroll
        for (int j = 0; j < 4; j++) {
            int n = n0 + tx * 4 + j;
            size_t o = (size_t)(m0 + ty * 4 + i) * D + n;
            h[o] = h[o] + acc[i][j] + b[n];
        }
}

// ---------------- final transform: t = relu(h@ft1+b1)@ft2+b2, q-mask ----------------
__global__ __launch_bounds__(64) void k_transform(const float* __restrict__ h,
                                                  const float* __restrict__ w1,
                                                  const float* __restrict__ b1,
                                                  const float* __restrict__ w2,
                                                  const float* __restrict__ b2,
                                                  float* __restrict__ tout) {
    __shared__ float row[D];
    __shared__ float hid[TT];
    int i = blockIdx.x;
    int j = threadIdx.x;  // 0..63
    row[j] = h[(size_t)i * D + j];
    row[j + 64] = h[(size_t)i * D + j + 64];
    __syncthreads();
    float s = b1[j];
    for (int k = 0; k < D; k++) s += row[k] * w1[k * TT + j];
    hid[j] = fmaxf(s, 0.f);
    __syncthreads();
    float o = b2[j];
    for (int k = 0; k < TT; k++) o += hid[k] * w2[k * TT + j];
    int p = i % NPG;
    if (p >= NQQ && p < NCC) o = 0.f;  // q-part rows >= NQ are masked
    tout[(size_t)i * TT + j] = o;
}

// ---------------- per-graph Sinkhorn + scoring ----------------
__global__ __launch_bounds__(256) void k_sinkhorn(const float* __restrict__ h,
                                                  const float* __restrict__ tall,
                                                  float* __restrict__ out) {
    __shared__ float la[NCC * NCC];
    __shared__ float tqs[NCC][TT];
    __shared__ float tcs[NCC][TT];
    __shared__ float ce[NCC][D];
    __shared__ float lse[NCC];
    __shared__ float red[256];
    int g = blockIdx.x;
    int tid = threadIdx.x;
    for (int idx = tid; idx < NCC * TT; idx += 256) {
        int r = idx / TT, k = idx % TT;
        tqs[r][k] = tall[(size_t)(g * NPG + r) * TT + k];
        tcs[r][k] = tall[(size_t)(g * NPG + NCC + r) * TT + k];
    }
    for (int idx = tid; idx < NCC * D; idx += 256) {
        int c = idx / D, d = idx % D;
        ce[c][d] = h[(size_t)(g * NPG + NCC + c) * D + d];
    }
    __syncthreads();
    for (int e = tid; e < NCC * NCC; e += 256) {
        int q = e / NCC, c = e % NCC;
        float s = 0.f;
        for (int k = 0; k < TT; k++) s += tqs[q][k] * tcs[c][k];
        la[e] = s * 10.0f;  // / SK_TEMP
    }
    __syncthreads();
    for (int it = 0; it < SKI; ++it) {
        if (tid < NCC) {
            float m = -INFINITY;
            for (int c = 0; c < NCC; c++) m = fmaxf(m, la[tid * NCC + c]);
            float s = 0.f;
            for (int c = 0; c < NCC; c++) s += expf(la[tid * NCC + c] - m);
            lse[tid] = m + logf(s);
        }
        __syncthreads();
        for (int e = tid; e < NCC * NCC; e += 256) la[e] -= lse[e / NCC];
        __syncthreads();
        if (tid < NCC) {
            float m = -INFINITY;
            for (int q = 0; q < NCC; q++) m = fmaxf(m, la[q * NCC + tid]);
            float s = 0.f;
            for (int q = 0; q < NCC; q++) s += expf(la[q * NCC + tid] - m);
            lse[tid] = m + logf(s);
        }
        __syncthreads();
        for (int e = tid; e < NCC * NCC; e += 256) la[e] -= lse[e % NCC];
        __syncthreads();
    }
    for (int e = tid; e < NCC * NCC; e += 256) la[e] = expf(la[e]);
    __syncthreads();
    float part = 0.f;
    for (int idx = tid; idx < NCC * D; idx += 256) {
        int q = idx / D, d = idx % D;
        float mv = 0.f;
        for (int c = 0; c < NCC; c++) mv += la[q * NCC + c] * ce[c][d];
        float qe = h[(size_t)(g * NPG + q) * D + d];
        part += fmaxf(qe - mv, 0.f);
    }
    red[tid] = part;
    __syncthreads();
    for (int s2 = 128; s2 > 0; s2 >>= 1) {
        if (tid < s2) red[tid] += red[tid + s2];
        __syncthreads();
    }
    if (tid == 0) out[g] = -red[0];
}

extern "C" void kernel_launch(void* const* d_in, const int* in_sizes, int n_in,
                              void* d_out, int out_size, void* d_ws, size_t ws_size,
                              hipStream_t stream) {
    const float* nf  = (const float*)d_in[0];
    const float* ef  = (const float*)d_in[1];
    const float* mfi = (const float*)d_in[2];
    const float* enw = (const float*)d_in[3];
    const float* enb = (const float*)d_in[4];
    const float* eew = (const float*)d_in[5];
    const float* eeb = (const float*)d_in[6];
    const float* mw1 = (const float*)d_in[7];
    const float* mb1 = (const float*)d_in[8];
    const float* mw2 = (const float*)d_in[9];
    const float* mb2 = (const float*)d_in[10];
    const float* uw1 = (const float*)d_in[11];
    const float* ub1 = (const float*)d_in[12];
    const float* uw2 = (const float*)d_in[13];
    const float* ub2 = (const float*)d_in[14];
    const float* f1w = (const float*)d_in[15];
    const float* f1b = (const float*)d_in[16];
    const float* f2w = (const float*)d_in[17];
    const float* f2b = (const float*)d_in[18];
    const int* fr = (const int*)d_in[19];
    const int* to = (const int*)d_in[20];
    float* out = (float*)d_out;

    float* ws   = (float*)d_ws;
    float* h    = ws;                             // NN*128
    float* H1c  = h + (size_t)NN * D;             // 11520*512 (reused as U: NN*256)
    float* agg  = H1c + (size_t)NC_ROWS * 512;    // NN*128
    float* uv   = agg + (size_t)NN * D;           // 512
    float* tall = uv + 512;                       // NN*64

    k_encode<<<(NN * D + 255) / 256, 256, 0, stream>>>(nf, enw, enb, h);
    k_prep_uv<<<1, 256, 0, stream>>>(eew, eeb, mw1, mb1, uv);

    for (int it = 0; it < NPROP; ++it) {
        k_h1c<<<dim3(NC_ROWS / 64, 8), 256, 0, stream>>>(h, mw1, H1c);
        k_edge_g<<<dim3(BATCH, 2), 256, 0, stream>>>(H1c, uv, fr, to, ef, mfi, mw2,
                                                     mb2, agg);
        k_upd1<<<dim3(NN / 64, 4), 256, 0, stream>>>(agg, h, uw1, ub1, H1c);
        k_upd2<<<dim3(NN / 64, 2), 256, 0, stream>>>(H1c, uw2, ub2, h);
    }

    k_transform<<<NN, 64, 0, stream>>>(h, f1w, f1b, f2w, f2b, tall);
    k_sinkhorn<<<BATCH, 256, 0, stream>>>(h, tall, out);
}

// Round 4
// 600.136 us; speedup vs baseline: 1.6297x; 1.5938x over previous
//
#include <hip/hip_runtime.h>

#define NN 15360        // total nodes
#define NCR 11520       // compacted H1 rows: 45 per graph (q 0..14, c 30..59)
#define EPG 135         // active edges per graph, contiguous per graph
#define BATCH 256
#define D 128
#define TT 64
#define NPG 60
#define NCC 30
#define NQQ 15
#define NPROP 5
#define SKI 10

typedef __attribute__((ext_vector_type(8))) short bf16x8;
typedef __attribute__((ext_vector_type(4))) float f32x4;

__device__ __forceinline__ float bf2f(unsigned short u) {
    union { float f; unsigned int i; } t;
    t.i = ((unsigned int)u) << 16;
    return t.f;
}
__device__ __forceinline__ unsigned short f2bf(float f) {
    union { float f; unsigned int i; } t;
    t.f = f;
    unsigned int r = t.i + 0x7fffu + ((t.i >> 16) & 1u);
    return (unsigned short)(r >> 16);
}
// split v = hi + lo with |lo| <= 2^-9 |v|; residual after pair ~2^-18
__device__ __forceinline__ void split_bf(float v, unsigned short& hi, unsigned short& lo) {
    hi = f2bf(v);
    lo = f2bf(v - bf2f(hi));
}

// ---------------- node encode: h[i,d] = nf[i]*w[d]+b[d]; fp32 + split ----------------
__global__ void k_encode(const float* __restrict__ nf, const float* __restrict__ w,
                         const float* __restrict__ b, float* __restrict__ h,
                         unsigned short* __restrict__ h_hi, unsigned short* __restrict__ h_lo) {
    int idx = blockIdx.x * 256 + threadIdx.x;
    if (idx >= NN * D) return;
    int d = idx & (D - 1);
    int i = idx >> 7;
    float v = nf[i] * w[d] + b[d];
    h[idx] = v;
    unsigned short hi, lo;
    split_bf(v, hi, lo);
    h_hi[idx] = hi;
    h_lo[idx] = lo;
}

// ---------------- edge-constant precompute: uv (512 fp32) ----------------
__global__ void k_prep_uv(const float* __restrict__ ew, const float* __restrict__ eb,
                          const float* __restrict__ w1, const float* __restrict__ b1,
                          float* __restrict__ uv) {
    int t = threadIdx.x;  // 0..255
    float u = 0.f, v = 0.f;
    for (int d = 0; d < D; ++d) {
        float wv = w1[(256 + d) * 256 + t];
        u += ew[d] * wv;
        v += eb[d] * wv;
    }
    uv[t] = u;
    uv[256 + t] = v + b1[t];
}

// ---------------- weight prep: transpose to [n][k], split into hi/lo bf16 -----------
__global__ void k_prep_w(const float* __restrict__ mw1, const float* __restrict__ mw2,
                         const float* __restrict__ uw1, const float* __restrict__ uw2,
                         unsigned short* __restrict__ w1th, unsigned short* __restrict__ w1tl,
                         unsigned short* __restrict__ w2th, unsigned short* __restrict__ w2tl,
                         unsigned short* __restrict__ uw1th, unsigned short* __restrict__ uw1tl,
                         unsigned short* __restrict__ uw2th, unsigned short* __restrict__ uw2tl) {
    int idx = blockIdx.x * 256 + threadIdx.x;
    float v;
    unsigned short *ph, *pl;
    int o;
    if (idx < 65536) {  // w1t [512][128]
        int n = idx >> 7, k = idx & 127;
        v = (n < 256) ? mw1[k * 256 + n] : mw1[(128 + k) * 256 + (n - 256)];
        ph = w1th; pl = w1tl; o = idx;
    } else if (idx < 98304) {  // w2t [128][256]
        o = idx - 65536;
        int n = o >> 8, k = o & 255;
        v = mw2[k * 128 + n];
        ph = w2th; pl = w2tl;
    } else if (idx < 163840) {  // uw1t [256][256]
        o = idx - 98304;
        int n = o >> 8, k = o & 255;
        v = uw1[k * 256 + n];
        ph = uw1th; pl = uw1tl;
    } else if (idx < 196608) {  // uw2t [128][256]
        o = idx - 163840;
        int n = o >> 8, k = o & 255;
        v = uw2[k * 128 + n];
        ph = uw2th; pl = uw2tl;
    } else {
        return;
    }
    unsigned short hi, lo;
    split_bf(v, hi, lo);
    ph[o] = hi;
    pl[o] = lo;
}

// ===== dense split-MFMA GEMMs: BM=128, BN=128, BK=64, 4 waves (2x2), 3-term =====
// LDS row stride 72 ushorts (144B = 9x16B, odd -> conflict-free b128 reads)

// ---- H1c(11520 x 512) fp32 = gather(h) @ w1t^T ----
__global__ __launch_bounds__(256) void k_h1c_mf(const unsigned short* __restrict__ h_hi,
                                                const unsigned short* __restrict__ h_lo,
                                                const unsigned short* __restrict__ w1th,
                                                const unsigned short* __restrict__ w1tl,
                                                float* __restrict__ H1c) {
    __shared__ unsigned short AsH[128 * 72], AsL[128 * 72];
    __shared__ unsigned short BsH[128 * 72], BsL[128 * 72];
    __shared__ int rowNode[128];
    int m0 = blockIdx.x * 128, n0 = blockIdx.y * 128;
    int tid = threadIdx.x;
    int lane = tid & 63, wid = tid >> 6;
    int wr = wid >> 1, wc = wid & 1;
    if (tid < 128) {
        int m = m0 + tid;
        int g = m / 45;
        int p = m - g * 45;
        rowNode[tid] = g * 60 + (p < 15 ? p : p + 15);
    }
    f32x4 acc[4][4] = {};
    for (int k0 = 0; k0 < 128; k0 += 64) {
        __syncthreads();
        for (int c = tid; c < 1024; c += 256) {
            int row = c >> 3, kc = c & 7;
            size_t asrc = (size_t)rowNode[row] * D + k0 + kc * 8;
            *(uint4*)&AsH[row * 72 + kc * 8] = *(const uint4*)&h_hi[asrc];
            *(uint4*)&AsL[row * 72 + kc * 8] = *(const uint4*)&h_lo[asrc];
            size_t bsrc = (size_t)(n0 + row) * 128 + k0 + kc * 8;
            *(uint4*)&BsH[row * 72 + kc * 8] = *(const uint4*)&w1th[bsrc];
            *(uint4*)&BsL[row * 72 + kc * 8] = *(const uint4*)&w1tl[bsrc];
        }
        __syncthreads();
#pragma unroll
        for (int kk = 0; kk < 2; ++kk) {
            int koff = kk * 32 + (lane >> 4) * 8;
            bf16x8 ah[4], al[4], bh[4], bl[4];
#pragma unroll
            for (int i = 0; i < 4; i++) {
                int r = (wr * 64 + i * 16 + (lane & 15)) * 72 + koff;
                ah[i] = *(bf16x8*)&AsH[r];
                al[i] = *(bf16x8*)&AsL[r];
            }
#pragma unroll
            for (int j = 0; j < 4; j++) {
                int r = (wc * 64 + j * 16 + (lane & 15)) * 72 + koff;
                bh[j] = *(bf16x8*)&BsH[r];
                bl[j] = *(bf16x8*)&BsL[r];
            }
#pragma unroll
            for (int i = 0; i < 4; i++)
#pragma unroll
                for (int j = 0; j < 4; j++) {
                    acc[i][j] = __builtin_amdgcn_mfma_f32_16x16x32_bf16(ah[i], bh[j], acc[i][j], 0, 0, 0);
                    acc[i][j] = __builtin_amdgcn_mfma_f32_16x16x32_bf16(al[i], bh[j], acc[i][j], 0, 0, 0);
                    acc[i][j] = __builtin_amdgcn_mfma_f32_16x16x32_bf16(ah[i], bl[j], acc[i][j], 0, 0, 0);
                }
        }
    }
    int rloc = (lane >> 4) * 4;
#pragma unroll
    for (int i = 0; i < 4; i++)
#pragma unroll
        for (int j = 0; j < 4; j++) {
            int col = n0 + wc * 64 + j * 16 + (lane & 15);
#pragma unroll
            for (int r = 0; r < 4; r++) {
                int m = m0 + wr * 64 + i * 16 + rloc + r;
                H1c[(size_t)m * 512 + col] = acc[i][j][r];
            }
        }
}

// ---- U(15360 x 256) = relu([agg|h] @ uw1t^T + b1), split out ----
__global__ __launch_bounds__(256) void k_upd1_mf(const unsigned short* __restrict__ agg_hi,
                                                 const unsigned short* __restrict__ agg_lo,
                                                 const unsigned short* __restrict__ h_hi,
                                                 const unsigned short* __restrict__ h_lo,
                                                 const unsigned short* __restrict__ uw1th,
                                                 const unsigned short* __restrict__ uw1tl,
                                                 const float* __restrict__ b1,
                                                 unsigned short* __restrict__ Ub_hi,
                                                 unsigned short* __restrict__ Ub_lo) {
    __shared__ unsigned short AsH[128 * 72], AsL[128 * 72];
    __shared__ unsigned short BsH[128 * 72], BsL[128 * 72];
    int m0 = blockIdx.x * 128, n0 = blockIdx.y * 128;
    int tid = threadIdx.x;
    int lane = tid & 63, wid = tid >> 6;
    int wr = wid >> 1, wc = wid & 1;
    f32x4 acc[4][4] = {};
    for (int k0 = 0; k0 < 256; k0 += 64) {
        __syncthreads();
        const unsigned short* srcH = (k0 < 128) ? agg_hi : h_hi;
        const unsigned short* srcL = (k0 < 128) ? agg_lo : h_lo;
        int kb = (k0 < 128) ? k0 : (k0 - 128);
        for (int c = tid; c < 1024; c += 256) {
            int row = c >> 3, kc = c & 7;
            size_t asrc = (size_t)(m0 + row) * D + kb + kc * 8;
            *(uint4*)&AsH[row * 72 + kc * 8] = *(const uint4*)&srcH[asrc];
            *(uint4*)&AsL[row * 72 + kc * 8] = *(const uint4*)&srcL[asrc];
            size_t bsrc = (size_t)(n0 + row) * 256 + k0 + kc * 8;
            *(uint4*)&BsH[row * 72 + kc * 8] = *(const uint4*)&uw1th[bsrc];
            *(uint4*)&BsL[row * 72 + kc * 8] = *(const uint4*)&uw1tl[bsrc];
        }
        __syncthreads();
#pragma unroll
        for (int kk = 0; kk < 2; ++kk) {
            int koff = kk * 32 + (lane >> 4) * 8;
            bf16x8 ah[4], al[4], bh[4], bl[4];
#pragma unroll
            for (int i = 0; i < 4; i++) {
                int r = (wr * 64 + i * 16 + (lane & 15)) * 72 + koff;
                ah[i] = *(bf16x8*)&AsH[r];
                al[i] = *(bf16x8*)&AsL[r];
            }
#pragma unroll
            for (int j = 0; j < 4; j++) {
                int r = (wc * 64 + j * 16 + (lane & 15)) * 72 + koff;
                bh[j] = *(bf16x8*)&BsH[r];
                bl[j] = *(bf16x8*)&BsL[r];
            }
#pragma unroll
            for (int i = 0; i < 4; i++)
#pragma unroll
                for (int j = 0; j < 4; j++) {
                    acc[i][j] = __builtin_amdgcn_mfma_f32_16x16x32_bf16(ah[i], bh[j], acc[i][j], 0, 0, 0);
                    acc[i][j] = __builtin_amdgcn_mfma_f32_16x16x32_bf16(al[i], bh[j], acc[i][j], 0, 0, 0);
                    acc[i][j] = __builtin_amdgcn_mfma_f32_16x16x32_bf16(ah[i], bl[j], acc[i][j], 0, 0, 0);
                }
        }
    }
    int rloc = (lane >> 4) * 4;
#pragma unroll
    for (int i = 0; i < 4; i++)
#pragma unroll
        for (int j = 0; j < 4; j++) {
            int col = n0 + wc * 64 + j * 16 + (lane & 15);
            float bias = b1[col];
#pragma unroll
            for (int r = 0; r < 4; r++) {
                int m = m0 + wr * 64 + i * 16 + rloc + r;
                float v = fmaxf(acc[i][j][r] + bias, 0.f);
                unsigned short hi, lo;
                split_bf(v, hi, lo);
                Ub_hi[(size_t)m * 256 + col] = hi;
                Ub_lo[(size_t)m * 256 + col] = lo;
            }
        }
}

// ---- h(15360x128) += U @ uw2t^T + b2 ; fp32 residual + re-split h ----
__global__ __launch_bounds__(256) void k_upd2_mf(const unsigned short* __restrict__ Ub_hi,
                                                 const unsigned short* __restrict__ Ub_lo,
                                                 const unsigned short* __restrict__ uw2th,
                                                 const unsigned short* __restrict__ uw2tl,
                                                 const float* __restrict__ b2,
                                                 float* __restrict__ h,
                                                 unsigned short* __restrict__ h_hi,
                                                 unsigned short* __restrict__ h_lo) {
    __shared__ unsigned short AsH[128 * 72], AsL[128 * 72];
    __shared__ unsigned short BsH[128 * 72], BsL[128 * 72];
    int m0 = blockIdx.x * 128;
    int tid = threadIdx.x;
    int lane = tid & 63, wid = tid >> 6;
    int wr = wid >> 1, wc = wid & 1;
    f32x4 acc[4][4] = {};
    for (int k0 = 0; k0 < 256; k0 += 64) {
        __syncthreads();
        for (int c = tid; c < 1024; c += 256) {
            int row = c >> 3, kc = c & 7;
            size_t asrc = (size_t)(m0 + row) * 256 + k0 + kc * 8;
            *(uint4*)&AsH[row * 72 + kc * 8] = *(const uint4*)&Ub_hi[asrc];
            *(uint4*)&AsL[row * 72 + kc * 8] = *(const uint4*)&Ub_lo[asrc];
            size_t bsrc = (size_t)row * 256 + k0 + kc * 8;
            *(uint4*)&BsH[row * 72 + kc * 8] = *(const uint4*)&uw2th[bsrc];
            *(uint4*)&BsL[row * 72 + kc * 8] = *(const uint4*)&uw2tl[bsrc];
        }
        __syncthreads();
#pragma unroll
        for (int kk = 0; kk < 2; ++kk) {
            int koff = kk * 32 + (lane >> 4) * 8;
            bf16x8 ah[4], al[4], bh[4], bl[4];
#pragma unroll
            for (int i = 0; i < 4; i++) {
                int r = (wr * 64 + i * 16 + (lane & 15)) * 72 + koff;
                ah[i] = *(bf16x8*)&AsH[r];
                al[i] = *(bf16x8*)&AsL[r];
            }
#pragma unroll
            for (int j = 0; j < 4; j++) {
                int r = (wc * 64 + j * 16 + (lane & 15)) * 72 + koff;
                bh[j] = *(bf16x8*)&BsH[r];
                bl[j] = *(bf16x8*)&BsL[r];
            }
#pragma unroll
            for (int i = 0; i < 4; i++)
#pragma unroll
                for (int j = 0; j < 4; j++) {
                    acc[i][j] = __builtin_amdgcn_mfma_f32_16x16x32_bf16(ah[i], bh[j], acc[i][j], 0, 0, 0);
                    acc[i][j] = __builtin_amdgcn_mfma_f32_16x16x32_bf16(al[i], bh[j], acc[i][j], 0, 0, 0);
                    acc[i][j] = __builtin_amdgcn_mfma_f32_16x16x32_bf16(ah[i], bl[j], acc[i][j], 0, 0, 0);
                }
        }
    }
    int rloc = (lane >> 4) * 4;
#pragma unroll
    for (int i = 0; i < 4; i++)
#pragma unroll
        for (int j = 0; j < 4; j++) {
            int col = wc * 64 + j * 16 + (lane & 15);
            float bias = b2[col];
#pragma unroll
            for (int r = 0; r < 4; r++) {
                int m = m0 + wr * 64 + i * 16 + rloc + r;
                size_t o = (size_t)m * D + col;
                float v = h[o] + acc[i][j][r] + bias;
                h[o] = v;
                unsigned short hi, lo;
                split_bf(v, hi, lo);
                h_hi[o] = hi;
                h_lo[o] = lo;
            }
        }
}

// ===== per-graph edge pass, split-MFMA: M=144(135), N=128, K=256 =====
__global__ __launch_bounds__(256) void k_edge_mf(const float* __restrict__ H1c,
                                                 const float* __restrict__ uv,
                                                 const int* __restrict__ fr,
                                                 const int* __restrict__ to,
                                                 const float* __restrict__ ef,
                                                 const float* __restrict__ mfi,
                                                 const unsigned short* __restrict__ w2th,
                                                 const unsigned short* __restrict__ w2tl,
                                                 const float* __restrict__ b2,
                                                 unsigned short* __restrict__ agg_hi,
                                                 unsigned short* __restrict__ agg_lo) {
    __shared__ unsigned short AsH[144 * 40], AsL[144 * 40];  // stride 80B (5x16B)
    __shared__ unsigned short BsH[128 * 40], BsL[128 * 40];
    __shared__ float aggl[NPG][128];
    __shared__ float uvl[512];
    __shared__ int cfs[144], ctc[144], ctl[144];
    __shared__ float efs[144], ms_[144];
    int g = blockIdx.x;
    int tid = threadIdx.x;
    int lane = tid & 63, wid = tid >> 6;
    int e0 = g * EPG;
    if (tid < 144) {
        if (tid < EPG) {
            int f = fr[e0 + tid] - g * 60;
            int t = to[e0 + tid] - g * 60;
            cfs[tid] = g * 45 + (f < 15 ? f : f - 15);
            ctc[tid] = g * 45 + (t < 15 ? t : t - 15);
            ctl[tid] = t;
            efs[tid] = ef[e0 + tid];
            ms_[tid] = mfi[e0 + tid];
        } else {
            cfs[tid] = 0; ctc[tid] = 0; ctl[tid] = 0; efs[tid] = 0.f; ms_[tid] = 0.f;
        }
    }
    for (int i = tid; i < 512; i += 256) uvl[i] = uv[i];
    for (int i = tid; i < NPG * 128; i += 256) (&aggl[0][0])[i] = 0.f;
    f32x4 acc[9][2] = {};
    for (int ks = 0; ks < 8; ++ks) {
        __syncthreads();
        // A: Z = relu(H1[from][k] + H1[to][256+k] + ef*u + v) in fp32, split to hi/lo
        for (int c = tid; c < 576; c += 256) {
            int row = c >> 2, kc = c & 3;
            int k = ks * 32 + kc * 8;
            const float* pf = H1c + (size_t)cfs[row] * 512 + k;
            const float* pt = H1c + (size_t)ctc[row] * 512 + 256 + k;
            float e_ = efs[row];
            float4 f0 = *(const float4*)pf, f1 = *(const float4*)(pf + 4);
            float4 t0 = *(const float4*)pt, t1 = *(const float4*)(pt + 4);
            float zf[8] = {f0.x + t0.x, f0.y + t0.y, f0.z + t0.z, f0.w + t0.w,
                           f1.x + t1.x, f1.y + t1.y, f1.z + t1.z, f1.w + t1.w};
            unsigned int ph[4], pl[4];
#pragma unroll
            for (int t = 0; t < 4; t++) {
                float z0 = fmaxf(zf[2 * t]     + e_ * uvl[k + 2 * t]     + uvl[256 + k + 2 * t], 0.f);
                float z1 = fmaxf(zf[2 * t + 1] + e_ * uvl[k + 2 * t + 1] + uvl[256 + k + 2 * t + 1], 0.f);
                unsigned short h0, l0, h1, l1;
                split_bf(z0, h0, l0);
                split_bf(z1, h1, l1);
                ph[t] = (unsigned int)h0 | ((unsigned int)h1 << 16);
                pl[t] = (unsigned int)l0 | ((unsigned int)l1 << 16);
            }
            *(uint4*)&AsH[row * 40 + kc * 8] = make_uint4(ph[0], ph[1], ph[2], ph[3]);
            *(uint4*)&AsL[row * 40 + kc * 8] = make_uint4(pl[0], pl[1], pl[2], pl[3]);
        }
        // B: w2t split slices
        for (int c = tid; c < 512; c += 256) {
            int row = c >> 2, kc = c & 3;
            size_t bsrc = (size_t)row * 256 + ks * 32 + kc * 8;
            *(uint4*)&BsH[row * 40 + kc * 8] = *(const uint4*)&w2th[bsrc];
            *(uint4*)&BsL[row * 40 + kc * 8] = *(const uint4*)&w2tl[bsrc];
        }
        __syncthreads();
        int koff = (lane >> 4) * 8;
        bf16x8 bh[2], bl[2];
#pragma unroll
        for (int j = 0; j < 2; j++) {
            int r = (wid * 32 + j * 16 + (lane & 15)) * 40 + koff;
            bh[j] = *(bf16x8*)&BsH[r];
            bl[j] = *(bf16x8*)&BsL[r];
        }
#pragma unroll
        for (int i = 0; i < 9; i++) {
            int r = (i * 16 + (lane & 15)) * 40 + koff;
            bf16x8 ah = *(bf16x8*)&AsH[r];
            bf16x8 al = *(bf16x8*)&AsL[r];
#pragma unroll
            for (int j = 0; j < 2; j++) {
                acc[i][j] = __builtin_amdgcn_mfma_f32_16x16x32_bf16(ah, bh[j], acc[i][j], 0, 0, 0);
                acc[i][j] = __builtin_amdgcn_mfma_f32_16x16x32_bf16(al, bh[j], acc[i][j], 0, 0, 0);
                acc[i][j] = __builtin_amdgcn_mfma_f32_16x16x32_bf16(ah, bl[j], acc[i][j], 0, 0, 0);
            }
        }
    }
    __syncthreads();
    int rloc = (lane >> 4) * 4;
#pragma unroll
    for (int i = 0; i < 9; i++)
#pragma unroll
        for (int j = 0; j < 2; j++) {
            int col = wid * 32 + j * 16 + (lane & 15);
            float bias = b2[col];
#pragma unroll
            for (int r = 0; r < 4; r++) {
                int e = i * 16 + rloc + r;
                if (e < EPG) {
                    float val = (acc[i][j][r] + bias) * ms_[e];
                    atomicAdd(&aggl[ctl[e]][col], val);
                }
            }
        }
    __syncthreads();
    for (int idx = tid; idx < NPG * 128; idx += 256) {
        int r = idx >> 7, c = idx & 127;
        float val = aggl[r][c];
        unsigned short hi, lo;
        split_bf(val, hi, lo);
        size_t o = (size_t)(g * NPG + r) * D + c;
        agg_hi[o] = hi;
        agg_lo[o] = lo;
    }
}

// ---------------- final transform: t = relu(h@ft1+b1)@ft2+b2, q-mask (fp32) --------
__global__ __launch_bounds__(64) void k_transform(const float* __restrict__ h,
                                                  const float* __restrict__ w1,
                                                  const float* __restrict__ b1,
                                                  const float* __restrict__ w2,
                                                  const float* __restrict__ b2,
                                                  float* __restrict__ tout) {
    __shared__ float row[D];
    __shared__ float hid[TT];
    int i = blockIdx.x;
    int j = threadIdx.x;  // 0..63
    row[j] = h[(size_t)i * D + j];
    row[j + 64] = h[(size_t)i * D + j + 64];
    __syncthreads();
    float s = b1[j];
    for (int k = 0; k < D; k++) s += row[k] * w1[k * TT + j];
    hid[j] = fmaxf(s, 0.f);
    __syncthreads();
    float o = b2[j];
    for (int k = 0; k < TT; k++) o += hid[k] * w2[k * TT + j];
    int p = i % NPG;
    if (p >= NQQ && p < NCC) o = 0.f;
    tout[(size_t)i * TT + j] = o;
}

// ---------------- per-graph Sinkhorn + scoring (fp32) ----------------
__global__ __launch_bounds__(256) void k_sinkhorn(const float* __restrict__ h,
                                                  const float* __restrict__ tall,
                                                  float* __restrict__ out) {
    __shared__ float la[NCC * NCC];
    __shared__ float tqs[NCC][TT];
    __shared__ float tcs[NCC][TT];
    __shared__ float ce[NCC][D];
    __shared__ float lse[NCC];
    __shared__ float red[256];
    int g = blockIdx.x;
    int tid = threadIdx.x;
    for (int idx = tid; idx < NCC * TT; idx += 256) {
        int r = idx / TT, k = idx % TT;
        tqs[r][k] = tall[(size_t)(g * NPG + r) * TT + k];
        tcs[r][k] = tall[(size_t)(g * NPG + NCC + r) * TT + k];
    }
    for (int idx = tid; idx < NCC * D; idx += 256) {
        int c = idx / D, d = idx % D;
        ce[c][d] = h[(size_t)(g * NPG + NCC + c) * D + d];
    }
    __syncthreads();
    for (int e = tid; e < NCC * NCC; e += 256) {
        int q = e / NCC, c = e % NCC;
        float s = 0.f;
        for (int k = 0; k < TT; k++) s += tqs[q][k] * tcs[c][k];
        la[e] = s * 10.0f;
    }
    __syncthreads();
    for (int it = 0; it < SKI; ++it) {
        if (tid < NCC) {
            float m = -INFINITY;
            for (int c = 0; c < NCC; c++) m = fmaxf(m, la[tid * NCC + c]);
            float s = 0.f;
            for (int c = 0; c < NCC; c++) s += expf(la[tid * NCC + c] - m);
            lse[tid] = m + logf(s);
        }
        __syncthreads();
        for (int e = tid; e < NCC * NCC; e += 256) la[e] -= lse[e / NCC];
        __syncthreads();
        if (tid < NCC) {
            float m = -INFINITY;
            for (int q = 0; q < NCC; q++) m = fmaxf(m, la[q * NCC + tid]);
            float s = 0.f;
            for (int q = 0; q < NCC; q++) s += expf(la[q * NCC + tid] - m);
            lse[tid] = m + logf(s);
        }
        __syncthreads();
        for (int e = tid; e < NCC * NCC; e += 256) la[e] -= lse[e % NCC];
        __syncthreads();
    }
    for (int e = tid; e < NCC * NCC; e += 256) la[e] = expf(la[e]);
    __syncthreads();
    float part = 0.f;
    for (int idx = tid; idx < NCC * D; idx += 256) {
        int q = idx / D, d = idx % D;
        float mv = 0.f;
        for (int c = 0; c < NCC; c++) mv += la[q * NCC + c] * ce[c][d];
        float qe = h[(size_t)(g * NPG + q) * D + d];
        part += fmaxf(qe - mv, 0.f);
    }
    red[tid] = part;
    __syncthreads();
    for (int s2 = 128; s2 > 0; s2 >>= 1) {
        if (tid < s2) red[tid] += red[tid + s2];
        __syncthreads();
    }
    if (tid == 0) out[g] = -red[0];
}

extern "C" void kernel_launch(void* const* d_in, const int* in_sizes, int n_in,
                              void* d_out, int out_size, void* d_ws, size_t ws_size,
                              hipStream_t stream) {
    const float* nf  = (const float*)d_in[0];
    const float* ef  = (const float*)d_in[1];
    const float* mfi = (const float*)d_in[2];
    const float* enw = (const float*)d_in[3];
    const float* enb = (const float*)d_in[4];
    const float* eew = (const float*)d_in[5];
    const float* eeb = (const float*)d_in[6];
    const float* mw1 = (const float*)d_in[7];
    const float* mb1 = (const float*)d_in[8];
    const float* mw2 = (const float*)d_in[9];
    const float* mb2 = (const float*)d_in[10];
    const float* uw1 = (const float*)d_in[11];
    const float* ub1 = (const float*)d_in[12];
    const float* uw2 = (const float*)d_in[13];
    const float* ub2 = (const float*)d_in[14];
    const float* f1w = (const float*)d_in[15];
    const float* f1b = (const float*)d_in[16];
    const float* f2w = (const float*)d_in[17];
    const float* f2b = (const float*)d_in[18];
    const int* fr = (const int*)d_in[19];
    const int* to = (const int*)d_in[20];
    float* out = (float*)d_out;

    // workspace layout
    char* base = (char*)d_ws;
    size_t off = 0;
    float* h = (float*)(base + off);                 off += (size_t)NN * D * 4;
    unsigned short* h_hi = (unsigned short*)(base + off); off += (size_t)NN * D * 2;
    unsigned short* h_lo = (unsigned short*)(base + off); off += (size_t)NN * D * 2;
    // H1c fp32 region; Ub hi/lo pair aliases it (phase-disjoint within an iteration)
    float* H1c = (float*)(base + off);
    unsigned short* Ub_hi = (unsigned short*)H1c;
    unsigned short* Ub_lo = Ub_hi + (size_t)NN * 256;
    off += (size_t)NCR * 512 * 4;
    unsigned short* agg_hi = (unsigned short*)(base + off); off += (size_t)NN * D * 2;
    unsigned short* agg_lo = (unsigned short*)(base + off); off += (size_t)NN * D * 2;
    unsigned short* w1th = (unsigned short*)(base + off); off += 65536 * 2;
    unsigned short* w1tl = (unsigned short*)(base + off); off += 65536 * 2;
    unsigned short* w2th = (unsigned short*)(base + off); off += 32768 * 2;
    unsigned short* w2tl = (unsigned short*)(base + off); off += 32768 * 2;
    unsigned short* uw1th = (unsigned short*)(base + off); off += 65536 * 2;
    unsigned short* uw1tl = (unsigned short*)(base + off); off += 65536 * 2;
    unsigned short* uw2th = (unsigned short*)(base + off); off += 32768 * 2;
    unsigned short* uw2tl = (unsigned short*)(base + off); off += 32768 * 2;
    float* uv = (float*)(base + off); off += 512 * 4;
    float* tall = (float*)agg_hi;  // alias: transform runs after the loop, agg dead

    k_encode<<<(NN * D + 255) / 256, 256, 0, stream>>>(nf, enw, enb, h, h_hi, h_lo);
    k_prep_uv<<<1, 256, 0, stream>>>(eew, eeb, mw1, mb1, uv);
    k_prep_w<<<768, 256, 0, stream>>>(mw1, mw2, uw1, uw2, w1th, w1tl, w2th, w2tl,
                                      uw1th, uw1tl, uw2th, uw2tl);

    for (int it = 0; it < NPROP; ++it) {
        k_h1c_mf<<<dim3(NCR / 128, 4), 256, 0, stream>>>(h_hi, h_lo, w1th, w1tl, H1c);
        k_edge_mf<<<BATCH, 256, 0, stream>>>(H1c, uv, fr, to, ef, mfi, w2th, w2tl,
                                             mb2, agg_hi, agg_lo);
        k_upd1_mf<<<dim3(NN / 128, 2), 256, 0, stream>>>(agg_hi, agg_lo, h_hi, h_lo,
                                                         uw1th, uw1tl, ub1, Ub_hi, Ub_lo);
        k_upd2_mf<<<dim3(NN / 128, 1), 256, 0, stream>>>(Ub_hi, Ub_lo, uw2th, uw2tl,
                                                         ub2, h, h_hi, h_lo);
    }

    k_transform<<<NN, 64, 0, stream>>>(h, f1w, f1b, f2w, f2b, tall);
    k_sinkhorn<<<BATCH, 256, 0, stream>>>(h, tall, out);
}